// Round 1
// baseline (1284.045 us; speedup 1.0000x reference)
//
#include <hip/hip_runtime.h>
#include <hip/hip_bf16.h>

#define BB 2
#define SS 2048
#define DMODEL 1024
#define NH 16
#define DHEAD 64
#define NEGINF (-1e10f)

typedef __attribute__((ext_vector_type(8))) short short8;
typedef __attribute__((ext_vector_type(4))) short short4v;
typedef __attribute__((ext_vector_type(4))) float f32x4;
typedef __hip_bfloat16 bf16;

__device__ __forceinline__ bf16 tobf(float x){ return __float2bfloat16(x); }
__device__ __forceinline__ float tof(bf16 x){ return __bfloat162float(x); }

// async global->LDS, 16B per lane. dst is wave-uniform base; HW adds lane*16.
__device__ __forceinline__ void gl_lds16(const void* g, void* l){
  __builtin_amdgcn_global_load_lds(
      (const __attribute__((address_space(1))) unsigned int*)g,
      (__attribute__((address_space(3))) unsigned int*)l, 16, 0, 0);
}

// ---------------- conversion kernels ----------------

// X [R][1024] f32 -> X3 [R][3072] bf16, A-pattern segments [hi | lo | hi]
__global__ __launch_bounds__(256) void k_a3(const float* __restrict__ X, bf16* __restrict__ X3){
  long i = ((long)blockIdx.x*256 + threadIdx.x)*4;
  long r = i >> 10; int k = (int)(i & 1023);
  float4 x = *(const float4*)(X + i);
  float xs[4] = {x.x, x.y, x.z, x.w};
  alignas(8) bf16 hb[4], lb[4];
  #pragma unroll
  for(int j=0;j<4;j++){ hb[j]=tobf(xs[j]); lb[j]=tobf(xs[j]-tof(hb[j])); }
  bf16* base = X3 + r*3072 + k;
  *(short4v*)(base)        = *(short4v*)hb;
  *(short4v*)(base + 1024) = *(short4v*)lb;
  *(short4v*)(base + 2048) = *(short4v*)hb;
}

// plain f32 -> bf16 elementwise (4 elems/thread)
__global__ __launch_bounds__(256) void k_vbf(const float* __restrict__ X, bf16* __restrict__ Y){
  long i = ((long)blockIdx.x*256 + threadIdx.x)*4;
  float4 x = *(const float4*)(X + i);
  alignas(8) bf16 b[4] = {tobf(x.x), tobf(x.y), tobf(x.z), tobf(x.w)};
  *(short4v*)(Y + i) = *(short4v*)b;
}

// W [1024][1024] f32 (K x N) -> out bf16 transposed.
// MODE 0: out [N][1024] = plain bf16(W^T)
// MODE 1: out [N][3072] B-pattern segments [hi | hi | lo]
template<int MODE>
__global__ __launch_bounds__(256) void k_wt(const float* __restrict__ W, bf16* __restrict__ out){
  __shared__ float t[64][65];
  const int kb = blockIdx.y*64, nb = blockIdx.x*64;
  const int tid = threadIdx.x;
  const int r = tid>>2, cq = tid&3;
  #pragma unroll
  for(int i=0;i<4;i++){
    float4 x = *(const float4*)&W[(long)(kb+r)*1024 + nb + cq*16 + i*4];
    t[r][cq*16+i*4+0]=x.x; t[r][cq*16+i*4+1]=x.y; t[r][cq*16+i*4+2]=x.z; t[r][cq*16+i*4+3]=x.w;
  }
  __syncthreads();
  alignas(16) bf16 hb[16], lb[16];
  #pragma unroll
  for(int i=0;i<16;i++){
    float x = t[cq*16+i][r];
    hb[i] = tobf(x);
    lb[i] = tobf(x - tof(hb[i]));
  }
  if (MODE==0){
    bf16* o = out + (long)(nb+r)*1024 + kb + cq*16;
    ((short8*)o)[0] = ((short8*)hb)[0]; ((short8*)o)[1] = ((short8*)hb)[1];
  } else {
    bf16* o = out + (long)(nb+r)*3072 + kb + cq*16;
    ((short8*)(o))[0]        = ((short8*)hb)[0]; ((short8*)(o))[1]        = ((short8*)hb)[1];
    ((short8*)(o+1024))[0]   = ((short8*)hb)[0]; ((short8*)(o+1024))[1]   = ((short8*)hb)[1];
    ((short8*)(o+2048))[0]   = ((short8*)lb)[0]; ((short8*)(o+2048))[1]   = ((short8*)lb)[1];
  }
}

// vp_bf [4096][1024] bf16 -> vpt [32 bh][64 d][2048 s] bf16 (head transpose)
__global__ __launch_bounds__(256) void k_vt(const bf16* __restrict__ vp, bf16* __restrict__ vpt){
  __shared__ alignas(16) bf16 t[64][72];
  const int sb = blockIdx.x*64;
  const int bh = blockIdx.y, b = bh>>4, h = bh&15;
  const int tid = threadIdx.x;
  {
    const int r = tid>>2, cg = tid&3;
    const bf16* src = vp + (long)(b*SS + sb + r)*DMODEL + h*64 + cg*16;
    *(short8*)&t[r][cg*16]   = *(const short8*)(src);
    *(short8*)&t[r][cg*16+8] = *(const short8*)(src+8);
  }
  __syncthreads();
  {
    const int d = tid>>2, sg = tid&3;
    alignas(16) bf16 ob[16];
    #pragma unroll
    for(int i=0;i<16;i++) ob[i] = t[sg*16+i][d];
    bf16* dst = vpt + ((long)bh*DHEAD + d)*SS + sb + sg*16;
    ((short8*)dst)[0] = ((short8*)ob)[0]; ((short8*)dst)[1] = ((short8*)ob)[1];
  }
}

// ---------------- main GEMM: C[M][N] = A[M][K] @ Bt[N][K]^T ----------------
// 128x128 tile, BK=32, 4 waves (2x2), 16x16x32 bf16 MFMA, LDS double-buffer.
enum { EPI_F32BIAS=0, EPI_BF16=1, EPI_SCORES=2, EPI_SPL3A=3, EPI_SPL3B=4 };

template<int EPI>
__global__ __launch_bounds__(256)
void gemm128(const bf16* __restrict__ A, int lda, long sAz,
             const bf16* __restrict__ Bt, int ldb, long sBz,
             float* __restrict__ Cf, bf16* __restrict__ Cb,
             int ldc, long sCz,
             const float* __restrict__ bias,
             const int* __restrict__ mask,
             float scale, int K)
{
  __shared__ alignas(16) bf16 lds[2][2][128*32];
  const int tid = threadIdx.x, wid = tid>>6, lane = tid&63;
  const int wr = wid>>1, wc = wid&1;
  const long bz = blockIdx.z;
  const int rowB = blockIdx.y*128, colB = blockIdx.x*128;
  const bf16* Ab = A + bz*sAz;
  const bf16* Bb = Bt + bz*sBz;

  auto stage = [&](int buf, int kt){
    #pragma unroll
    for(int i=0;i<2;i++){
      const int r0 = wid*32 + i*16;
      const char* ga = (const char*)(Ab + (long)(rowB + r0 + (lane>>2))*lda + kt*32) + (lane&3)*16;
      gl_lds16(ga, (char*)&lds[buf][0][0] + r0*64);
      const char* gb = (const char*)(Bb + (long)(colB + r0 + (lane>>2))*ldb + kt*32) + (lane&3)*16;
      gl_lds16(gb, (char*)&lds[buf][1][0] + r0*64);
    }
  };

  f32x4 acc[4][4];
  #pragma unroll
  for(int m=0;m<4;m++){
    #pragma unroll
    for(int n=0;n<4;n++){ acc[m][n][0]=0.f; acc[m][n][1]=0.f; acc[m][n][2]=0.f; acc[m][n][3]=0.f; }
  }

  const int nk = K/32;
  stage(0,0);
  int cur=0;
  for(int kt=0; kt<nk; ++kt){
    __syncthreads();                       // staged tile [cur] complete (vmcnt drain)
    if (kt+1<nk) stage(cur^1, kt+1);       // async prefetch next tile
    const bf16* la = &lds[cur][0][0];
    const bf16* lb = &lds[cur][1][0];
    const int rr = lane&15, kq = (lane>>4)*8;
    short8 af[4], bg[4];
    #pragma unroll
    for(int m=0;m<4;m++) af[m] = *(const short8*)(la + (wr*64+m*16+rr)*32 + kq);
    #pragma unroll
    for(int n=0;n<4;n++) bg[n] = *(const short8*)(lb + (wc*64+n*16+rr)*32 + kq);
    #pragma unroll
    for(int m=0;m<4;m++){
      #pragma unroll
      for(int n=0;n<4;n++)
        acc[m][n] = __builtin_amdgcn_mfma_f32_16x16x32_bf16(af[m], bg[n], acc[m][n], 0,0,0);
    }
    cur ^= 1;
  }

  // epilogue: C/D layout col=lane&15, row=(lane>>4)*4+j  [m89-verified]
  #pragma unroll
  for(int m=0;m<4;m++){
    #pragma unroll
    for(int n=0;n<4;n++){
      const int row0 = rowB + wr*64 + m*16 + ((lane>>4)<<2);
      const int col  = colB + wc*64 + n*16 + (lane&15);
      #pragma unroll
      for(int j=0;j<4;j++){
        const int row = row0 + j;
        float x = acc[m][n][j];
        if constexpr (EPI==EPI_F32BIAS){
          Cf[bz*sCz + (long)row*ldc + col] = x + bias[col];
        } else if constexpr (EPI==EPI_BF16){
          Cb[bz*sCz + (long)row*ldc + col] = tobf(x + bias[col]);
        } else if constexpr (EPI==EPI_SCORES){
          const int b = (int)(bz>>4);
          const float s = x*scale;
          const int mv = mask[((long)b*SS + row)*SS + col];
          Cf[bz*sCz + (long)row*ldc + col] = (mv==0) ? NEGINF : s;
        } else {
          const float s = x + bias[col];
          const int b = row>>11, sq = row&2047;
          const int h = col>>6,  d  = col&63;
          bf16 hi = tobf(s);
          bf16 lo = tobf(s - tof(hi));
          bf16* o = Cb + (((long)(b*NH+h)*SS + sq)*192);
          if constexpr (EPI==EPI_SPL3A){ o[d]=hi; o[64+d]=lo; o[128+d]=hi; }  // A-pattern
          else                          { o[d]=hi; o[64+d]=hi; o[128+d]=lo; }  // B-pattern
        }
      }
    }
  }
}

// ---------------- PV GEMM: O = P(fp32, reg-staged->bf16) @ Vt^T ----------------
// per z=(b,h): P [2048][2048] fp32, Vt [64][2048] bf16 -> Obf rows into [4096][1024]
__global__ __launch_bounds__(256)
void gemm_pv(const float* __restrict__ P, const bf16* __restrict__ Vt, bf16* __restrict__ O)
{
  __shared__ alignas(16) bf16 lA[2][128*32];
  __shared__ alignas(16) bf16 lB[2][64*32];
  const int tid=threadIdx.x, wid=tid>>6, lane=tid&63;
  const long z = blockIdx.z;
  const int b = (int)(z>>4), h = (int)(z&15);
  const int rowB = blockIdx.y*128;
  const float* Pz = P + z*((long)SS*SS) + (long)rowB*SS;
  const bf16*  Vz = Vt + z*((long)DHEAD*SS);

  auto stageB = [&](int buf, int kt){
    const char* g = (const char*)(Vz + (long)(wid*16 + (lane>>2))*SS + kt*32) + (lane&3)*16;
    gl_lds16(g, (char*)&lB[buf][0] + wid*16*64);
  };
  const int ar = tid>>1, acg = tid&1;     // A-tile: row 0..127, 16-col group
  auto loadA = [&](int kt, float4* f){
    const float* src = Pz + (long)ar*SS + kt*32 + acg*16;
    #pragma unroll
    for(int i=0;i<4;i++) f[i] = *(const float4*)(src + i*4);
  };
  auto writeA = [&](int buf, const float4* f){
    alignas(16) bf16 tmp[16];
    #pragma unroll
    for(int i=0;i<4;i++){
      tmp[i*4+0]=tobf(f[i].x); tmp[i*4+1]=tobf(f[i].y);
      tmp[i*4+2]=tobf(f[i].z); tmp[i*4+3]=tobf(f[i].w);
    }
    short8* d = (short8*)(&lA[buf][ar*32 + acg*16]);
    d[0] = ((short8*)tmp)[0]; d[1] = ((short8*)tmp)[1];
  };

  f32x4 acc[2][4];
  #pragma unroll
  for(int m=0;m<2;m++){
    #pragma unroll
    for(int n=0;n<4;n++){ acc[m][n][0]=0.f; acc[m][n][1]=0.f; acc[m][n][2]=0.f; acc[m][n][3]=0.f; }
  }

  float4 fr[4];
  loadA(0, fr); stageB(0,0); writeA(0, fr);
  int cur=0;
  const int nk = SS/32;
  for(int kt=0; kt<nk; ++kt){
    __syncthreads();
    float4 fn[4];
    if (kt+1<nk){ stageB(cur^1, kt+1); loadA(kt+1, fn); }   // issue loads early (T14)
    const int rr=lane&15, kq=(lane>>4)*8;
    short8 af[2], bg[4];
    #pragma unroll
    for(int m=0;m<2;m++) af[m] = *(const short8*)(&lA[cur][(wid*32+m*16+rr)*32 + kq]);
    #pragma unroll
    for(int n=0;n<4;n++) bg[n] = *(const short8*)(&lB[cur][(n*16+rr)*32 + kq]);
    #pragma unroll
    for(int m=0;m<2;m++){
      #pragma unroll
      for(int n=0;n<4;n++)
        acc[m][n] = __builtin_amdgcn_mfma_f32_16x16x32_bf16(af[m], bg[n], acc[m][n], 0,0,0);
    }
    if (kt+1<nk) writeA(cur^1, fn);                          // convert+write late
    cur ^= 1;
  }

  #pragma unroll
  for(int m=0;m<2;m++){
    #pragma unroll
    for(int n=0;n<4;n++){
      const int row0 = rowB + wid*32 + m*16 + ((lane>>4)<<2);
      const int col  = n*16 + (lane&15);
      #pragma unroll
      for(int j=0;j<4;j++){
        const int row = row0 + j;
        O[((long)(b*SS + row))*DMODEL + h*64 + col] = tobf(acc[m][n][j]);
      }
    }
  }
}

// ---------------- masked softmax, in-place, one wave per row ----------------
__global__ __launch_bounds__(256) void k_softmax(float* __restrict__ attn){
  const long row = (long)blockIdx.x*4 + (threadIdx.x>>6);
  const int lane = threadIdx.x & 63;
  float* p = attn + row*SS;
  float v[32];
  float mx = -3.0e38f;
  #pragma unroll
  for(int i=0;i<8;i++){
    float4 t = *(const float4*)(p + i*256 + lane*4);
    v[i*4+0]=t.x; v[i*4+1]=t.y; v[i*4+2]=t.z; v[i*4+3]=t.w;
    mx = fmaxf(mx, fmaxf(fmaxf(t.x,t.y), fmaxf(t.z,t.w)));
  }
  #pragma unroll
  for(int off=32; off; off>>=1) mx = fmaxf(mx, __shfl_xor(mx, off));
  float sum = 0.f;
  #pragma unroll
  for(int i=0;i<32;i++){ v[i] = __expf(v[i]-mx); sum += v[i]; }
  #pragma unroll
  for(int off=32; off; off>>=1) sum += __shfl_xor(sum, off);
  const float inv = 1.0f/sum;
  #pragma unroll
  for(int i=0;i<8;i++){
    float4 t = { v[i*4+0]*inv, v[i*4+1]*inv, v[i*4+2]*inv, v[i*4+3]*inv };
    *(float4*)(p + i*256 + lane*4) = t;
  }
}

// ---------------- launch ----------------
extern "C" void kernel_launch(void* const* d_in, const int* in_sizes, int n_in,
                              void* d_out, int out_size, void* d_ws, size_t ws_size,
                              hipStream_t stream) {
  const float* q    = (const float*)d_in[0];
  const float* k    = (const float*)d_in[1];
  const float* v    = (const float*)d_in[2];
  const int*   mask = (const int*)  d_in[3];
  const float* Wq   = (const float*)d_in[4];
  const float* bq   = (const float*)d_in[5];
  const float* Wk   = (const float*)d_in[6];
  const float* bk   = (const float*)d_in[7];
  const float* Wv   = (const float*)d_in[8];
  const float* bv   = (const float*)d_in[9];
  const float* Wo   = (const float*)d_in[10];
  const float* bo   = (const float*)d_in[11];

  float* out  = (float*)d_out;                     // [2][2048][1024]
  float* attn = out + (long)BB*SS*DMODEL;          // [2][16][2048][2048]

  char* ws = (char*)d_ws;
  size_t o = 0;
  bf16* A3q = (bf16*)(ws+o); o += (size_t)4096*3072*2;   // 25.2 MB
  bf16* A3k = (bf16*)(ws+o); o += (size_t)4096*3072*2;
  bf16* vbf = (bf16*)(ws+o); o += (size_t)4096*1024*2;   // 8.4 MB
  bf16* Wq3 = (bf16*)(ws+o); o += (size_t)1024*3072*2;   // 6.3 MB
  bf16* Wk3 = (bf16*)(ws+o); o += (size_t)1024*3072*2;
  bf16* Wvt = (bf16*)(ws+o); o += (size_t)1024*1024*2;   // 2.1 MB
  bf16* Wot = (bf16*)(ws+o); o += (size_t)1024*1024*2;
  bf16* q3  = (bf16*)(ws+o); o += (size_t)32*2048*192*2; // 25.2 MB
  bf16* k3  = (bf16*)(ws+o); o += (size_t)32*2048*192*2;
  bf16* vpb = (bf16*)(ws+o); o += (size_t)4096*1024*2;
  bf16* vpt = (bf16*)(ws+o); o += (size_t)32*64*2048*2;  // 8.4 MB
  bf16* abf = (bf16*)(ws+o); o += (size_t)4096*1024*2;

  dim3 blk(256);
  // input conversions
  k_a3 <<<4096, blk, 0, stream>>>(q, A3q);
  k_a3 <<<4096, blk, 0, stream>>>(k, A3k);
  k_vbf<<<4096, blk, 0, stream>>>(v, vbf);
  k_wt<1><<<dim3(16,16), blk, 0, stream>>>(Wq, Wq3);
  k_wt<1><<<dim3(16,16), blk, 0, stream>>>(Wk, Wk3);
  k_wt<0><<<dim3(16,16), blk, 0, stream>>>(Wv, Wvt);
  k_wt<0><<<dim3(16,16), blk, 0, stream>>>(Wo, Wot);
  // projections (split-bf16 K=3072 for q,k; plain K=1024 for v)
  gemm128<EPI_SPL3A><<<dim3(8,32,1), blk, 0, stream>>>(A3q,3072,0, Wq3,3072,0, nullptr,q3, 0,0, bq, nullptr, 0.f, 3072);
  gemm128<EPI_SPL3B><<<dim3(8,32,1), blk, 0, stream>>>(A3k,3072,0, Wk3,3072,0, nullptr,k3, 0,0, bk, nullptr, 0.f, 3072);
  gemm128<EPI_BF16 ><<<dim3(8,32,1), blk, 0, stream>>>(vbf,1024,0, Wvt,1024,0, nullptr,vpb, 1024,0, bv, nullptr, 0.f, 1024);
  k_vt<<<dim3(32,32), blk, 0, stream>>>(vpb, vpt);
  // scores = q3 @ k3^T * scale, masked -> attn region (raw masked scores)
  gemm128<EPI_SCORES><<<dim3(16,16,32), blk, 0, stream>>>(
      q3,192,(long)SS*192, k3,192,(long)SS*192, attn,nullptr, SS,(long)SS*SS,
      nullptr, mask, 0.125f, 192);
  // softmax in-place on attn
  k_softmax<<<(BB*NH*SS)/4, blk, 0, stream>>>(attn);
  // PV -> abf (attn_out bf16, natural [B,S,D] layout)
  gemm_pv<<<dim3(1,16,32), blk, 0, stream>>>(attn, vpt, abf);
  // output projection
  gemm128<EPI_F32BIAS><<<dim3(8,32,1), blk, 0, stream>>>(abf,1024,0, Wot,1024,0, out,nullptr, 1024,0, bo, nullptr, 0.f, 1024);
}

// Round 3
// 1099.771 us; speedup vs baseline: 1.1676x; 1.1676x over previous
//
#include <hip/hip_runtime.h>
#include <hip/hip_bf16.h>
#include <hip/hip_fp16.h>

#define BB 2
#define SS 2048
#define DMODEL 1024
#define NH 16
#define DHEAD 64
#define NEGINF (-1e10f)
#define MASKF16 (-65504.0f)

typedef __attribute__((ext_vector_type(8))) short short8;
typedef __attribute__((ext_vector_type(4))) short short4v;
typedef __attribute__((ext_vector_type(4))) float f32x4;
typedef __hip_bfloat16 bf16;

__device__ __forceinline__ bf16 tobf(float x){ return __float2bfloat16(x); }
__device__ __forceinline__ float tof(bf16 x){ return __bfloat162float(x); }

// async global->LDS, 16B per lane. dst is wave-uniform base; HW adds lane*16.
__device__ __forceinline__ void gl_lds16(const void* g, void* l){
  __builtin_amdgcn_global_load_lds(
      (const __attribute__((address_space(1))) unsigned int*)g,
      (__attribute__((address_space(3))) unsigned int*)l, 16, 0, 0);
}

// ---------------- conversion kernels ----------------

// mask int32 -> bit array (1 bit per element), wave ballot, 64 elems/wave
__global__ __launch_bounds__(256) void k_maskbits(const int* __restrict__ mask,
                                                  unsigned long long* __restrict__ bits){
  long t = (long)blockIdx.x*256 + threadIdx.x;
  int m = mask[t];
  unsigned long long bal = __ballot(m != 0);
  if ((threadIdx.x & 63) == 0) bits[t>>6] = bal;
}

// X [R][1024] f32 -> X3 [R][3072] bf16, A-pattern segments [hi | lo | hi]
__global__ __launch_bounds__(256) void k_a3(const float* __restrict__ X, bf16* __restrict__ X3){
  long i = ((long)blockIdx.x*256 + threadIdx.x)*4;
  long r = i >> 10; int k = (int)(i & 1023);
  float4 x = *(const float4*)(X + i);
  float xs[4] = {x.x, x.y, x.z, x.w};
  alignas(8) bf16 hb[4], lb[4];
  #pragma unroll
  for(int j=0;j<4;j++){ hb[j]=tobf(xs[j]); lb[j]=tobf(xs[j]-tof(hb[j])); }
  bf16* base = X3 + r*3072 + k;
  *(short4v*)(base)        = *(short4v*)hb;
  *(short4v*)(base + 1024) = *(short4v*)lb;
  *(short4v*)(base + 2048) = *(short4v*)hb;
}

// plain f32 -> bf16 elementwise (4 elems/thread)
__global__ __launch_bounds__(256) void k_vbf(const float* __restrict__ X, bf16* __restrict__ Y){
  long i = ((long)blockIdx.x*256 + threadIdx.x)*4;
  float4 x = *(const float4*)(X + i);
  alignas(8) bf16 b[4] = {tobf(x.x), tobf(x.y), tobf(x.z), tobf(x.w)};
  *(short4v*)(Y + i) = *(short4v*)b;
}

// W [1024][1024] f32 (K x N) -> out bf16 transposed.
// MODE 0: out [N][1024] = plain bf16(W^T)
// MODE 1: out [N][3072] B-pattern segments [hi | hi | lo]
template<int MODE>
__global__ __launch_bounds__(256) void k_wt(const float* __restrict__ W, bf16* __restrict__ out){
  __shared__ float t[64][65];
  const int kb = blockIdx.y*64, nb = blockIdx.x*64;
  const int tid = threadIdx.x;
  const int r = tid>>2, cq = tid&3;
  #pragma unroll
  for(int i=0;i<4;i++){
    float4 x = *(const float4*)&W[(long)(kb+r)*1024 + nb + cq*16 + i*4];
    t[r][cq*16+i*4+0]=x.x; t[r][cq*16+i*4+1]=x.y; t[r][cq*16+i*4+2]=x.z; t[r][cq*16+i*4+3]=x.w;
  }
  __syncthreads();
  alignas(16) bf16 hb[16], lb[16];
  #pragma unroll
  for(int i=0;i<16;i++){
    float x = t[cq*16+i][r];
    hb[i] = tobf(x);
    lb[i] = tobf(x - tof(hb[i]));
  }
  if (MODE==0){
    bf16* o = out + (long)(nb+r)*1024 + kb + cq*16;
    ((short8*)o)[0] = ((short8*)hb)[0]; ((short8*)o)[1] = ((short8*)hb)[1];
  } else {
    bf16* o = out + (long)(nb+r)*3072 + kb + cq*16;
    ((short8*)(o))[0]        = ((short8*)hb)[0]; ((short8*)(o))[1]        = ((short8*)hb)[1];
    ((short8*)(o+1024))[0]   = ((short8*)hb)[0]; ((short8*)(o+1024))[1]   = ((short8*)hb)[1];
    ((short8*)(o+2048))[0]   = ((short8*)lb)[0]; ((short8*)(o+2048))[1]   = ((short8*)lb)[1];
  }
}

// vp_bf [4096][1024] bf16 -> vpt [32 bh][64 d][2048 s] bf16 (head transpose)
__global__ __launch_bounds__(256) void k_vt(const bf16* __restrict__ vp, bf16* __restrict__ vpt){
  __shared__ alignas(16) bf16 t[64][72];
  const int sb = blockIdx.x*64;
  const int bh = blockIdx.y, b = bh>>4, h = bh&15;
  const int tid = threadIdx.x;
  {
    const int r = tid>>2, cg = tid&3;
    const bf16* src = vp + (long)(b*SS + sb + r)*DMODEL + h*64 + cg*16;
    *(short8*)&t[r][cg*16]   = *(const short8*)(src);
    *(short8*)&t[r][cg*16+8] = *(const short8*)(src+8);
  }
  __syncthreads();
  {
    const int d = tid>>2, sg = tid&3;
    alignas(16) bf16 ob[16];
    #pragma unroll
    for(int i=0;i<16;i++) ob[i] = t[sg*16+i][d];
    bf16* dst = vpt + ((long)bh*DHEAD + d)*SS + sb + sg*16;
    ((short8*)dst)[0] = ((short8*)ob)[0]; ((short8*)dst)[1] = ((short8*)ob)[1];
  }
}

// ---------------- main GEMM: C[M][N] = A[M][K] @ Bt[N][K]^T ----------------
// 128x128 tile, BK=32, 4 waves (2x2), 16x16x32 bf16 MFMA, LDS double-buffer.
enum { EPI_F32BIAS=0, EPI_BF16=1, EPI_SPL3A=3, EPI_SPL3B=4 };

template<int EPI>
__global__ __launch_bounds__(256)
void gemm128(const bf16* __restrict__ A, int lda, long sAz,
             const bf16* __restrict__ Bt, int ldb, long sBz,
             float* __restrict__ Cf, bf16* __restrict__ Cb,
             int ldc, long sCz,
             const float* __restrict__ bias,
             int K)
{
  __shared__ alignas(16) bf16 lds[2][2][128*32];
  const int tid = threadIdx.x, wid = tid>>6, lane = tid&63;
  const int wr = wid>>1, wc = wid&1;
  const long bz = blockIdx.z;
  const int rowB = blockIdx.y*128, colB = blockIdx.x*128;
  const bf16* Ab = A + bz*sAz;
  const bf16* Bb = Bt + bz*sBz;

  auto stage = [&](int buf, int kt){
    #pragma unroll
    for(int i=0;i<2;i++){
      const int r0 = wid*32 + i*16;
      const char* ga = (const char*)(Ab + (long)(rowB + r0 + (lane>>2))*lda + kt*32) + (lane&3)*16;
      gl_lds16(ga, (char*)&lds[buf][0][0] + r0*64);
      const char* gb = (const char*)(Bb + (long)(colB + r0 + (lane>>2))*ldb + kt*32) + (lane&3)*16;
      gl_lds16(gb, (char*)&lds[buf][1][0] + r0*64);
    }
  };

  f32x4 acc[4][4];
  #pragma unroll
  for(int m=0;m<4;m++){
    #pragma unroll
    for(int n=0;n<4;n++){ acc[m][n][0]=0.f; acc[m][n][1]=0.f; acc[m][n][2]=0.f; acc[m][n][3]=0.f; }
  }

  const int nk = K/32;
  stage(0,0);
  int cur=0;
  for(int kt=0; kt<nk; ++kt){
    __syncthreads();
    if (kt+1<nk) stage(cur^1, kt+1);
    const bf16* la = &lds[cur][0][0];
    const bf16* lb = &lds[cur][1][0];
    const int rr = lane&15, kq = (lane>>4)*8;
    short8 af[4], bg[4];
    #pragma unroll
    for(int m=0;m<4;m++) af[m] = *(const short8*)(la + (wr*64+m*16+rr)*32 + kq);
    #pragma unroll
    for(int n=0;n<4;n++) bg[n] = *(const short8*)(lb + (wc*64+n*16+rr)*32 + kq);
    #pragma unroll
    for(int m=0;m<4;m++){
      #pragma unroll
      for(int n=0;n<4;n++)
        acc[m][n] = __builtin_amdgcn_mfma_f32_16x16x32_bf16(af[m], bg[n], acc[m][n], 0,0,0);
    }
    cur ^= 1;
  }

  // epilogue: C/D layout col=lane&15, row=(lane>>4)*4+j  [m89-verified]
  #pragma unroll
  for(int m=0;m<4;m++){
    #pragma unroll
    for(int n=0;n<4;n++){
      const int row0 = rowB + wr*64 + m*16 + ((lane>>4)<<2);
      const int col  = colB + wc*64 + n*16 + (lane&15);
      #pragma unroll
      for(int j=0;j<4;j++){
        const int row = row0 + j;
        float x = acc[m][n][j];
        if constexpr (EPI==EPI_F32BIAS){
          Cf[bz*sCz + (long)row*ldc + col] = x + bias[col];
        } else if constexpr (EPI==EPI_BF16){
          Cb[bz*sCz + (long)row*ldc + col] = tobf(x + bias[col]);
        } else {
          const float s = x + bias[col];
          const int b = row>>11, sq = row&2047;
          const int h = col>>6,  d  = col&63;
          bf16 hi = tobf(s);
          bf16 lo = tobf(s - tof(hi));
          bf16* o = Cb + (((long)(b*NH+h)*SS + sq)*192);
          if constexpr (EPI==EPI_SPL3A){ o[d]=hi; o[64+d]=lo; o[128+d]=hi; }  // A-pattern
          else                          { o[d]=hi; o[64+d]=hi; o[128+d]=lo; }  // B-pattern
        }
      }
    }
  }
}

// ---------------- scores GEMM: S_f16 = mask(q3 @ k3^T * scale) + row stats ----------------
// grid (16,16,32); writes f16 scores (masked -> -65504) + per-64col (max,sumexp) partials
__global__ __launch_bounds__(256)
void gemm_scores(const bf16* __restrict__ A, const bf16* __restrict__ Bt,
                 const unsigned int* __restrict__ bits,
                 __half* __restrict__ Sf, float2* __restrict__ partials, float scale)
{
  __shared__ alignas(16) bf16 lds[2][2][128*32];
  __shared__ unsigned int bitlds[128][4];
  const int tid = threadIdx.x, wid = tid>>6, lane = tid&63;
  const int wr = wid>>1, wc = wid&1;
  const long z = blockIdx.z;
  const int b = (int)(z>>4);
  const int rowB = blockIdx.y*128, colB = blockIdx.x*128;
  const bf16* Ab = A + z*((long)SS*192);
  const bf16* Bb = Bt + z*((long)SS*192);

  auto stage = [&](int buf, int kt){
    #pragma unroll
    for(int i=0;i<2;i++){
      const int r0 = wid*32 + i*16;
      const char* ga = (const char*)(Ab + (long)(rowB + r0 + (lane>>2))*192 + kt*32) + (lane&3)*16;
      gl_lds16(ga, (char*)&lds[buf][0][0] + r0*64);
      const char* gb = (const char*)(Bb + (long)(colB + r0 + (lane>>2))*192 + kt*32) + (lane&3)*16;
      gl_lds16(gb, (char*)&lds[buf][1][0] + r0*64);
    }
  };

  f32x4 acc[4][4];
  #pragma unroll
  for(int m=0;m<4;m++){
    #pragma unroll
    for(int n=0;n<4;n++){ acc[m][n][0]=0.f; acc[m][n][1]=0.f; acc[m][n][2]=0.f; acc[m][n][3]=0.f; }
  }

  stage(0,0);
  int cur=0;
  for(int kt=0; kt<6; ++kt){
    __syncthreads();
    if (kt+1<6) stage(cur^1, kt+1);
    const bf16* la = &lds[cur][0][0];
    const bf16* lb = &lds[cur][1][0];
    const int rr = lane&15, kq = (lane>>4)*8;
    short8 af[4], bg[4];
    #pragma unroll
    for(int m=0;m<4;m++) af[m] = *(const short8*)(la + (wr*64+m*16+rr)*32 + kq);
    #pragma unroll
    for(int n=0;n<4;n++) bg[n] = *(const short8*)(lb + (wc*64+n*16+rr)*32 + kq);
    #pragma unroll
    for(int m=0;m<4;m++){
      #pragma unroll
      for(int n=0;n<4;n++)
        acc[m][n] = __builtin_amdgcn_mfma_f32_16x16x32_bf16(af[m], bg[n], acc[m][n], 0,0,0);
    }
    cur ^= 1;
  }

  // stage mask bits for this 128x128 tile into LDS
  if (tid < 128){
    *(uint4*)&bitlds[tid][0] =
        *(const uint4*)(bits + ((long)(b*SS + rowB + tid))*64 + (colB>>5));
  }
  __syncthreads();

  __half* Sz = Sf + z*((long)SS*SS);
  #pragma unroll
  for(int m=0;m<4;m++){
    #pragma unroll
    for(int j=0;j<4;j++){
      const int row_l = wr*64 + m*16 + ((lane>>4)<<2) + j;
      const long rowOff = (long)(rowB + row_l)*SS;
      float x[4];
      #pragma unroll
      for(int n=0;n<4;n++){
        const int col_l = wc*64 + n*16 + (lane&15);
        const unsigned w = bitlds[row_l][col_l>>5];
        const bool keep = (w >> (col_l&31)) & 1u;
        const float s = keep ? acc[m][n][j]*scale : MASKF16;
        const __half hh = __float2half(s);
        Sz[rowOff + colB + col_l] = hh;
        x[n] = __half2float(hh);   // stats on the rounded value (exact match with PV)
      }
      float mx = fmaxf(fmaxf(x[0],x[1]), fmaxf(x[2],x[3]));
      #pragma unroll
      for(int off=1; off<16; off<<=1) mx = fmaxf(mx, __shfl_xor(mx, off));
      float sm = __expf(x[0]-mx)+__expf(x[1]-mx)+__expf(x[2]-mx)+__expf(x[3]-mx);
      #pragma unroll
      for(int off=1; off<16; off<<=1) sm += __shfl_xor(sm, off);
      if ((lane&15)==0)
        partials[((long)z*SS + rowB + row_l)*32 + blockIdx.x*2 + wc] = make_float2(mx, sm);
    }
  }
}

// ---------------- combine partials -> per-row (M, 1/Z) ----------------
__global__ __launch_bounds__(256) void k_stats(const float2* __restrict__ partials,
                                               float2* __restrict__ stats){
  const long row = (long)blockIdx.x*4 + (threadIdx.x>>6);
  const int lane = threadIdx.x & 63;
  float2 pr = make_float2(-3.0e38f, 0.f);
  if (lane < 32) pr = partials[row*32 + lane];
  float M = pr.x;
  #pragma unroll
  for(int off=32; off; off>>=1) M = fmaxf(M, __shfl_xor(M, off));
  float v = (lane < 32) ? pr.y * __expf(pr.x - M) : 0.f;
  #pragma unroll
  for(int off=32; off; off>>=1) v += __shfl_xor(v, off);
  if (lane == 0) stats[row] = make_float2(M, 1.0f / v);
}

// ---------------- PV GEMM: normalize on the fly, write attn_w, O = P @ Vt^T ----------------
__global__ __launch_bounds__(256)
void gemm_pv(const __half* __restrict__ S, const float2* __restrict__ stats,
             const bf16* __restrict__ Vt, float* __restrict__ attnw, bf16* __restrict__ O)
{
  __shared__ alignas(16) bf16 lA[2][128*32];
  __shared__ alignas(16) bf16 lB[2][64*32];
  const int tid=threadIdx.x, wid=tid>>6, lane=tid&63;
  const long z = blockIdx.z;
  const int b = (int)(z>>4), h = (int)(z&15);
  const int rowB = blockIdx.y*128;
  const __half* Sz = S + z*((long)SS*SS) + (long)rowB*SS;
  float*       Wz = attnw + z*((long)SS*SS) + (long)rowB*SS;
  const bf16*  Vz = Vt + z*((long)DHEAD*SS);

  auto stageB = [&](int buf, int kt){
    const char* g = (const char*)(Vz + (long)(wid*16 + (lane>>2))*SS + kt*32) + (lane&3)*16;
    gl_lds16(g, (char*)&lB[buf][0] + wid*16*64);
  };
  const int ar = tid>>1, acg = tid&1;          // one row per thread, 16-col half
  const float2 st = stats[z*SS + rowB + ar];
  const float M = st.x, invZ = st.y;

  auto loadA = [&](int kt, short8* r){
    const short8* src = (const short8*)(Sz + (long)ar*SS + kt*32 + acg*16);
    r[0] = src[0]; r[1] = src[1];
  };
  auto procA = [&](int buf, int kt, const short8* r){
    const __half* hp = (const __half*)r;
    alignas(16) float p[16];
    #pragma unroll
    for(int i=0;i<16;i++) p[i] = __expf(__half2float(hp[i]) - M) * invZ;
    float* w = Wz + (long)ar*SS + kt*32 + acg*16;
    #pragma unroll
    for(int i=0;i<4;i++) *(float4*)(w + i*4) = *(float4*)&p[i*4];
    alignas(16) bf16 tmp[16];
    #pragma unroll
    for(int i=0;i<16;i++) tmp[i] = tobf(p[i]);
    short8* d = (short8*)(&lA[buf][ar*32 + acg*16]);
    d[0] = ((short8*)tmp)[0]; d[1] = ((short8*)tmp)[1];
  };

  f32x4 acc[2][4];
  #pragma unroll
  for(int m=0;m<2;m++){
    #pragma unroll
    for(int n=0;n<4;n++){ acc[m][n][0]=0.f; acc[m][n][1]=0.f; acc[m][n][2]=0.f; acc[m][n][3]=0.f; }
  }

  short8 fr[2];
  loadA(0, fr); stageB(0,0); procA(0, 0, fr);
  int cur=0;
  const int nk = SS/32;
  for(int kt=0; kt<nk; ++kt){
    __syncthreads();
    short8 fn[2];
    if (kt+1<nk){ stageB(cur^1, kt+1); loadA(kt+1, fn); }   // issue loads early (T14)
    const int rr=lane&15, kq=(lane>>4)*8;
    short8 af[2], bg[4];
    #pragma unroll
    for(int m=0;m<2;m++) af[m] = *(const short8*)(&lA[cur][(wid*32+m*16+rr)*32 + kq]);
    #pragma unroll
    for(int n=0;n<4;n++) bg[n] = *(const short8*)(&lB[cur][(n*16+rr)*32 + kq]);
    #pragma unroll
    for(int m=0;m<2;m++){
      #pragma unroll
      for(int n=0;n<4;n++)
        acc[m][n] = __builtin_amdgcn_mfma_f32_16x16x32_bf16(af[m], bg[n], acc[m][n], 0,0,0);
    }
    if (kt+1<nk) procA(cur^1, kt+1, fn);                    // exp/normalize + attn_w + LDS late
    cur ^= 1;
  }

  #pragma unroll
  for(int m=0;m<2;m++){
    #pragma unroll
    for(int n=0;n<4;n++){
      const int row0 = rowB + wid*32 + m*16 + ((lane>>4)<<2);
      const int col  = n*16 + (lane&15);
      #pragma unroll
      for(int j=0;j<4;j++){
        const int row = row0 + j;
        O[((long)(b*SS + row))*DMODEL + h*64 + col] = tobf(acc[m][n][j]);
      }
    }
  }
}

// ---------------- launch ----------------
extern "C" void kernel_launch(void* const* d_in, const int* in_sizes, int n_in,
                              void* d_out, int out_size, void* d_ws, size_t ws_size,
                              hipStream_t stream) {
  const float* q    = (const float*)d_in[0];
  const float* k    = (const float*)d_in[1];
  const float* v    = (const float*)d_in[2];
  const int*   mask = (const int*)  d_in[3];
  const float* Wq   = (const float*)d_in[4];
  const float* bq   = (const float*)d_in[5];
  const float* Wk   = (const float*)d_in[6];
  const float* bk   = (const float*)d_in[7];
  const float* Wv   = (const float*)d_in[8];
  const float* bv   = (const float*)d_in[9];
  const float* Wo   = (const float*)d_in[10];
  const float* bo   = (const float*)d_in[11];

  float* out  = (float*)d_out;                     // [2][2048][1024]
  float* attn = out + (long)BB*SS*DMODEL;          // [2][16][2048][2048] (attn_w, fp32)

  char* ws = (char*)d_ws;
  size_t o = 0;
  bf16* A3q = (bf16*)(ws+o); o += (size_t)4096*3072*2;
  bf16* A3k = (bf16*)(ws+o); o += (size_t)4096*3072*2;
  bf16* vbf = (bf16*)(ws+o); o += (size_t)4096*1024*2;
  bf16* Wq3 = (bf16*)(ws+o); o += (size_t)1024*3072*2;
  bf16* Wk3 = (bf16*)(ws+o); o += (size_t)1024*3072*2;
  bf16* Wvt = (bf16*)(ws+o); o += (size_t)1024*1024*2;
  bf16* Wot = (bf16*)(ws+o); o += (size_t)1024*1024*2;
  bf16* q3  = (bf16*)(ws+o); o += (size_t)32*2048*192*2;
  bf16* k3  = (bf16*)(ws+o); o += (size_t)32*2048*192*2;
  bf16* vpb = (bf16*)(ws+o); o += (size_t)4096*1024*2;
  bf16* vpt = (bf16*)(ws+o); o += (size_t)32*64*2048*2;
  bf16* abf = (bf16*)(ws+o); o += (size_t)4096*1024*2;
  unsigned long long* bits = (unsigned long long*)(ws+o); o += (size_t)BB*SS*32*8;  // 1 MB
  __half* scoresF = (__half*)(ws+o); o += (size_t)32*SS*SS*2;                       // 268 MB
  float2* partials = (float2*)(ws+o); o += (size_t)32*SS*32*8;                      // 16.8 MB
  float2* stats   = (float2*)(ws+o); o += (size_t)32*SS*8;                          // 0.5 MB

  dim3 blk(256);
  // input conversions
  k_maskbits<<<(BB*SS*SS)/256, blk, 0, stream>>>(mask, bits);
  k_a3 <<<4096, blk, 0, stream>>>(q, A3q);
  k_a3 <<<4096, blk, 0, stream>>>(k, A3k);
  k_vbf<<<4096, blk, 0, stream>>>(v, vbf);
  k_wt<1><<<dim3(16,16), blk, 0, stream>>>(Wq, Wq3);
  k_wt<1><<<dim3(16,16), blk, 0, stream>>>(Wk, Wk3);
  k_wt<0><<<dim3(16,16), blk, 0, stream>>>(Wv, Wvt);
  k_wt<0><<<dim3(16,16), blk, 0, stream>>>(Wo, Wot);
  // projections (split-bf16 K=3072 for q,k; plain K=1024 for v)
  gemm128<EPI_SPL3A><<<dim3(8,32,1), blk, 0, stream>>>(A3q,3072,0, Wq3,3072,0, nullptr,q3, 0,0, bq, 3072);
  gemm128<EPI_SPL3B><<<dim3(8,32,1), blk, 0, stream>>>(A3k,3072,0, Wk3,3072,0, nullptr,k3, 0,0, bk, 3072);
  gemm128<EPI_BF16 ><<<dim3(8,32,1), blk, 0, stream>>>(vbf,1024,0, Wvt,1024,0, nullptr,vpb, 1024,0, bv, 1024);
  k_vt<<<dim3(32,32), blk, 0, stream>>>(vpb, vpt);
  // scores (f16 + fused stats partials)
  gemm_scores<<<dim3(16,16,32), blk, 0, stream>>>(q3, k3, (const unsigned int*)bits,
                                                  scoresF, partials, 0.125f);
  // per-row (M, 1/Z)
  k_stats<<<(32*SS)/4, blk, 0, stream>>>(partials, stats);
  // PV: normalize + write attn_w fp32 + attn_out bf16
  gemm_pv<<<dim3(1,16,32), blk, 0, stream>>>(scoresF, stats, vpt, attn, abf);
  // output projection
  gemm128<EPI_F32BIAS><<<dim3(8,32,1), blk, 0, stream>>>(abf,1024,0, Wot,1024,0, out,nullptr, 1024,0, bo, 1024);
}